// Round 1
// baseline (1071.408 us; speedup 1.0000x reference)
//
#include <hip/hip_runtime.h>
#include <math.h>

#define N_POS 8192
#define FEAT 512
#define NTOT (2 * N_POS)
#define BM 128
#define BN 128
#define BK 32
#define PAD 4

__device__ inline unsigned long long packMax(float v, unsigned idx) {
    unsigned u = __float_as_uint(v);
    u = (u & 0x80000000u) ? ~u : (u | 0x80000000u);
    return ((unsigned long long)u << 32) | (unsigned)(~idx);
}
__device__ inline unsigned unpackIdx(unsigned long long p) {
    return ~(unsigned)(p & 0xffffffffull);
}

__global__ void init_ws(unsigned long long* buf, int n) {
    int i = blockIdx.x * blockDim.x + threadIdx.x;
    if (i < n) buf[i] = 0ull;
}

__global__ __launch_bounds__(256, 4) void gemm_argmax(
    const float* __restrict__ A, const float* __restrict__ B,
    const int* __restrict__ sidx, const int* __restrict__ tidx,
    unsigned long long* __restrict__ row_best,
    unsigned long long* __restrict__ col_best)
{
    __shared__ float As[BK][BM + PAD];
    __shared__ float Bs[BK][BN + PAD];
    __shared__ int sI[BM];
    __shared__ int tI[BN];
    __shared__ unsigned long long redR[BM];
    __shared__ unsigned long long redC[BN];

    const int tid = threadIdx.x;
    const int brow = blockIdx.x * BM;
    const int bcol = blockIdx.y * BN;

    if (tid < BM) { sI[tid] = sidx[brow + tid]; redR[tid] = 0ull; }
    else          { tI[tid - BM] = tidx[bcol + tid - BM]; redC[tid - BM] = 0ull; }
    __syncthreads();

    const int tx = tid & 15, ty = tid >> 4;
    float acc[8][8] = {};

    for (int k0 = 0; k0 < FEAT; k0 += BK) {
        #pragma unroll
        for (int l = 0; l < 4; ++l) {
            int idx4 = tid + l * 256;      // 0..1023 float4 slots (128 rows x 8)
            int r  = idx4 >> 3;
            int c4 = idx4 & 7;
            float4 va = *(const float4*)(A + (size_t)sI[r] * FEAT + k0 + c4 * 4);
            As[c4*4+0][r] = va.x; As[c4*4+1][r] = va.y;
            As[c4*4+2][r] = va.z; As[c4*4+3][r] = va.w;
            float4 vb = *(const float4*)(B + (size_t)tI[r] * FEAT + k0 + c4 * 4);
            Bs[c4*4+0][r] = vb.x; Bs[c4*4+1][r] = vb.y;
            Bs[c4*4+2][r] = vb.z; Bs[c4*4+3][r] = vb.w;
        }
        __syncthreads();
        #pragma unroll
        for (int kk = 0; kk < BK; ++kk) {
            float a[8], b[8];
            *(float4*)&a[0] = *(const float4*)&As[kk][ty * 8];
            *(float4*)&a[4] = *(const float4*)&As[kk][ty * 8 + 4];
            *(float4*)&b[0] = *(const float4*)&Bs[kk][tx * 8];
            *(float4*)&b[4] = *(const float4*)&Bs[kk][tx * 8 + 4];
            #pragma unroll
            for (int m = 0; m < 8; ++m)
                #pragma unroll
                for (int n = 0; n < 8; ++n)
                    acc[m][n] = fmaf(a[m], b[n], acc[m][n]);
        }
        __syncthreads();
    }

    // per-thread row maxima (strict > keeps first occurrence = smallest col)
    #pragma unroll
    for (int m = 0; m < 8; ++m) {
        float best = acc[m][0]; int bi = 0;
        #pragma unroll
        for (int n = 1; n < 8; ++n)
            if (acc[m][n] > best) { best = acc[m][n]; bi = n; }
        atomicMax(&redR[ty * 8 + m], packMax(best, (unsigned)(bcol + tx * 8 + bi)));
    }
    #pragma unroll
    for (int n = 0; n < 8; ++n) {
        float best = acc[0][n]; int bi = 0;
        #pragma unroll
        for (int m = 1; m < 8; ++m)
            if (acc[m][n] > best) { best = acc[m][n]; bi = m; }
        atomicMax(&redC[tx * 8 + n], packMax(best, (unsigned)(brow + ty * 8 + bi)));
    }
    __syncthreads();
    if (tid < BM) atomicMax(&row_best[brow + tid], redR[tid]);
    else          atomicMax(&col_best[bcol + tid - BM], redC[tid - BM]);
}

__global__ __launch_bounds__(1024) void finalize_loss(
    const float* __restrict__ T4,
    const float* __restrict__ src_points, const float* __restrict__ tgt_points,
    const float* __restrict__ src_scores, const float* __restrict__ tgt_scores,
    const int* __restrict__ sidx, const int* __restrict__ tidx,
    const unsigned long long* __restrict__ row_best,
    const unsigned long long* __restrict__ col_best,
    float* __restrict__ out)
{
    const int tid = threadIdx.x;
    const float R00=T4[0],R01=T4[1],R02=T4[2],t0=T4[3];
    const float R10=T4[4],R11=T4[5],R12=T4[6],t1=T4[7];
    const float R20=T4[8],R21=T4[9],R22=T4[10],t2=T4[11];

    double S1 = 0.0, S0 = 0.0;
    float cnt = 0.f, sumres = 0.f, corr = 0.f;

    for (int i = tid; i < NTOT; i += 1024) {
        float label, score;
        if (i < N_POS) {
            int si = sidx[i];
            const float* p = src_points + (size_t)si * 3;
            float px = R00*p[0]+R01*p[1]+R02*p[2]+t0;
            float py = R10*p[0]+R11*p[1]+R12*p[2]+t1;
            float pz = R20*p[0]+R21*p[1]+R22*p[2]+t2;
            unsigned nn = unpackIdx(row_best[i]);
            const float* q = tgt_points + (size_t)tidx[nn] * 3;
            float dx = px-q[0], dy = py-q[1], dz = pz-q[2];
            label = (sqrtf(dx*dx+dy*dy+dz*dz) < 0.1f) ? 1.f : 0.f;
            score = src_scores[si];
        } else {
            int j = i - N_POS;
            int tj = tidx[j];
            const float* q = tgt_points + (size_t)tj * 3;
            unsigned nn = unpackIdx(col_best[j]);
            int si = sidx[nn];
            const float* p = src_points + (size_t)si * 3;
            float px = R00*p[0]+R01*p[1]+R02*p[2]+t0;
            float py = R10*p[0]+R11*p[1]+R12*p[2]+t1;
            float pz = R20*p[0]+R21*p[1]+R22*p[2]+t2;
            float dx = q[0]-px, dy = q[1]-py, dz = q[2]-pz;
            label = (sqrtf(dx*dx+dy*dy+dz*dz) < 0.1f) ? 1.f : 0.f;
            score = tgt_scores[tj];
        }
        cnt += label;
        float res = (score > 0.5f) ? 1.f : 0.f;
        sumres += res;
        corr += res * label;
        if (label > 0.5f) S1 += (double)(-logf(score));
        else              S0 += (double)(-logf(1.0f - score));
    }

    #pragma unroll
    for (int off = 32; off > 0; off >>= 1) {
        S1 += __shfl_down(S1, off);
        S0 += __shfl_down(S0, off);
        cnt += __shfl_down(cnt, off);
        sumres += __shfl_down(sumres, off);
        corr += __shfl_down(corr, off);
    }
    __shared__ double sh1[16], sh0[16];
    __shared__ float shc[16], shr[16], shco[16];
    int wid = tid >> 6, lane = tid & 63;
    if (lane == 0) { sh1[wid]=S1; sh0[wid]=S0; shc[wid]=cnt; shr[wid]=sumres; shco[wid]=corr; }
    __syncthreads();
    if (tid == 0) {
        double s1 = 0, s0 = 0; float c = 0, r = 0, co = 0;
        for (int w = 0; w < 16; ++w) { s1+=sh1[w]; s0+=sh0[w]; c+=shc[w]; r+=shr[w]; co+=shco[w]; }
        float nw = c / (float)NTOT;
        float loss = (float)((nw * s1 + (1.0 - (double)nw) * s0) / (double)NTOT);
        float precision = co / (r + 1e-12f);
        float recall    = co / (c + 1e-12f);
        out[0] = loss; out[1] = precision; out[2] = recall;
    }
}

extern "C" void kernel_launch(void* const* d_in, const int* in_sizes, int n_in,
                              void* d_out, int out_size, void* d_ws, size_t ws_size,
                              hipStream_t stream) {
    const float* T4         = (const float*)d_in[0];
    const float* src_points = (const float*)d_in[1];
    const float* tgt_points = (const float*)d_in[2];
    const float* src_scores = (const float*)d_in[3];
    const float* tgt_scores = (const float*)d_in[4];
    const float* src_feats  = (const float*)d_in[5];
    const float* tgt_feats  = (const float*)d_in[6];
    const int*   sidx       = (const int*)d_in[7];
    const int*   tidx       = (const int*)d_in[8];

    unsigned long long* row_best = (unsigned long long*)d_ws;
    unsigned long long* col_best = row_best + N_POS;
    float* out = (float*)d_out;

    hipLaunchKernelGGL(init_ws, dim3(64), dim3(256), 0, stream, row_best, 2 * N_POS);
    hipLaunchKernelGGL(gemm_argmax, dim3(N_POS / BM, N_POS / BN), dim3(256), 0, stream,
                       src_feats, tgt_feats, sidx, tidx, row_best, col_best);
    hipLaunchKernelGGL(finalize_loss, dim3(1), dim3(1024), 0, stream,
                       T4, src_points, tgt_points, src_scores, tgt_scores,
                       sidx, tidx, row_best, col_best, out);
}

// Round 2
// 297.090 us; speedup vs baseline: 3.6063x; 3.6063x over previous
//
#include <hip/hip_runtime.h>
#include <math.h>

#define N_POS 8192
#define FEAT 512
#define NTOT (2 * N_POS)
#define BM 128
#define BN 128
#define BK 32
#define KSTEPS (FEAT / BK)

typedef __attribute__((ext_vector_type(8))) short bf16x8;
typedef __attribute__((ext_vector_type(4))) float f32x4;

__device__ inline unsigned long long packMax(float v, unsigned idx) {
    unsigned u = __float_as_uint(v);
    u = (u & 0x80000000u) ? ~u : (u | 0x80000000u);
    return ((unsigned long long)u << 32) | (unsigned)(~idx);
}
__device__ inline unsigned unpackIdx(unsigned long long p) {
    return ~(unsigned)(p & 0xffffffffull);
}

__global__ void init_ws(unsigned long long* buf, int n) {
    int i = blockIdx.x * blockDim.x + threadIdx.x;
    if (i < n) buf[i] = 0ull;
}

// split fp32 -> hi(bf16, RNE) + lo(bf16, trunc); 8 at a time
__device__ inline void split8(const float* f, bf16x8& hi, bf16x8& lo) {
    #pragma unroll
    for (int i = 0; i < 8; ++i) {
        unsigned u = __float_as_uint(f[i]);
        unsigned hr = (u + 0x7FFFu + ((u >> 16) & 1u)) >> 16;
        hi[i] = (short)hr;
        float lf = f[i] - __uint_as_float(hr << 16);
        lo[i] = (short)(__float_as_uint(lf) >> 16);
    }
}

// LDS tile: [row][64 bf16] = hi chunks 0-3 (k 0..31), lo chunks 4-7; chunk c stored at c^(row&7)
__device__ inline bf16x8 read_frag(const short (*S)[64], int row, int chunk) {
    int c = chunk ^ (row & 7);
    return *(const bf16x8*)&S[row][c * 8];
}
__device__ inline void write_chunk(short (*S)[64], int row, int chunk, bf16x8 v) {
    int c = chunk ^ (row & 7);
    *(bf16x8*)&S[row][c * 8] = v;
}

__global__ __launch_bounds__(256) void gemm_argmax(
    const float* __restrict__ A, const float* __restrict__ B,
    const int* __restrict__ sidx, const int* __restrict__ tidx,
    unsigned long long* __restrict__ row_best,
    unsigned long long* __restrict__ col_best)
{
    __shared__ short As[BM][64];
    __shared__ short Bs[BN][64];
    __shared__ int sI[BM], tI[BN];
    __shared__ unsigned long long redR[BM], redC[BN];

    const int tid = threadIdx.x;
    const int brow = blockIdx.x * BM;
    const int bcol = blockIdx.y * BN;

    if (tid < BM) { sI[tid] = sidx[brow + tid]; redR[tid] = 0ull; }
    else          { tI[tid - BM] = tidx[bcol + tid - BM]; redC[tid - BM] = 0ull; }
    __syncthreads();

    const int r = tid >> 1;          // 0..127: staged row
    const int h = tid & 1;           // k-half within BK (16 floats each)
    const float* aBase = A + (size_t)sI[r] * FEAT + h * 16;
    const float* bBase = B + (size_t)tI[r] * FEAT + h * 16;

    const int w = tid >> 6;
    const int wm = w >> 1, wn = w & 1;
    const int lane = tid & 63;
    const int l15 = lane & 15, khalf = lane >> 4;

    f32x4 acc[4][4];
    #pragma unroll
    for (int m = 0; m < 4; ++m)
        #pragma unroll
        for (int n = 0; n < 4; ++n)
            acc[m][n] = (f32x4)0.f;

    float4 pa[4], pb[4];
    #pragma unroll
    for (int i = 0; i < 4; ++i) {
        pa[i] = *(const float4*)(aBase + i * 4);
        pb[i] = *(const float4*)(bBase + i * 4);
    }

    for (int ks = 0; ks < KSTEPS; ++ks) {
        // convert staged regs -> LDS (hi/lo bf16, swizzled chunks)
        bf16x8 ha0, ha1, la0, la1, hb0, hb1, lb0, lb1;
        split8((const float*)&pa[0], ha0, la0);
        split8((const float*)&pa[2], ha1, la1);
        split8((const float*)&pb[0], hb0, lb0);
        split8((const float*)&pb[2], hb1, lb1);
        write_chunk(As, r, 2 * h,     ha0);
        write_chunk(As, r, 2 * h + 1, ha1);
        write_chunk(As, r, 4 + 2 * h, la0);
        write_chunk(As, r, 5 + 2 * h, la1);
        write_chunk(Bs, r, 2 * h,     hb0);
        write_chunk(Bs, r, 2 * h + 1, hb1);
        write_chunk(Bs, r, 4 + 2 * h, lb0);
        write_chunk(Bs, r, 5 + 2 * h, lb1);
        __syncthreads();

        if (ks + 1 < KSTEPS) {       // issue next tile's global loads early
            const float* ap = aBase + (ks + 1) * BK;
            const float* bp = bBase + (ks + 1) * BK;
            #pragma unroll
            for (int i = 0; i < 4; ++i) {
                pa[i] = *(const float4*)(ap + i * 4);
                pb[i] = *(const float4*)(bp + i * 4);
            }
        }

        bf16x8 ah[4], al[4], bh[4], bl[4];
        #pragma unroll
        for (int i = 0; i < 4; ++i) {
            int ra = wm * 64 + i * 16 + l15;
            ah[i] = read_frag(As, ra, khalf);
            al[i] = read_frag(As, ra, 4 + khalf);
            int rb = wn * 64 + i * 16 + l15;
            bh[i] = read_frag(Bs, rb, khalf);
            bl[i] = read_frag(Bs, rb, 4 + khalf);
        }
        #pragma unroll
        for (int m = 0; m < 4; ++m)
            #pragma unroll
            for (int n = 0; n < 4; ++n) {
                acc[m][n] = __builtin_amdgcn_mfma_f32_16x16x32_bf16(ah[m], bh[n], acc[m][n], 0, 0, 0);
                acc[m][n] = __builtin_amdgcn_mfma_f32_16x16x32_bf16(ah[m], bl[n], acc[m][n], 0, 0, 0);
                acc[m][n] = __builtin_amdgcn_mfma_f32_16x16x32_bf16(al[m], bh[n], acc[m][n], 0, 0, 0);
            }
        __syncthreads();
    }

    // ---- fused argmax epilogue ----
    // lane holds C[row = wm*64 + m*16 + khalf*4 + j][col = wn*64 + n*16 + l15]
    #pragma unroll
    for (int m = 0; m < 4; ++m) {
        #pragma unroll
        for (int j = 0; j < 4; ++j) {
            float best = acc[m][0][j]; int bn_ = 0;
            #pragma unroll
            for (int n = 1; n < 4; ++n)
                if (acc[m][n][j] > best) { best = acc[m][n][j]; bn_ = n; }
            unsigned long long p = packMax(best, (unsigned)(bcol + wn * 64 + bn_ * 16 + l15));
            #pragma unroll
            for (int mask = 1; mask <= 8; mask <<= 1) {
                unsigned long long q = __shfl_xor(p, mask);
                if (q > p) p = q;
            }
            if (l15 == 0)
                atomicMax(&redR[wm * 64 + m * 16 + khalf * 4 + j], p);
        }
    }
    #pragma unroll
    for (int n = 0; n < 4; ++n) {
        float best = acc[0][n][0]; int bm_ = 0, bj_ = 0;
        #pragma unroll
        for (int m = 0; m < 4; ++m)
            #pragma unroll
            for (int j = 0; j < 4; ++j)
                if (acc[m][n][j] > best) { best = acc[m][n][j]; bm_ = m; bj_ = j; }
        unsigned long long p = packMax(best, (unsigned)(brow + wm * 64 + bm_ * 16 + khalf * 4 + bj_));
        #pragma unroll
        for (int mask = 16; mask <= 32; mask <<= 1) {
            unsigned long long q = __shfl_xor(p, mask);
            if (q > p) p = q;
        }
        if (khalf == 0)
            atomicMax(&redC[wn * 64 + n * 16 + l15], p);
    }
    __syncthreads();
    if (tid < BM) atomicMax(&row_best[brow + tid], redR[tid]);
    else          atomicMax(&col_best[bcol + tid - BM], redC[tid - BM]);
}

__global__ __launch_bounds__(1024) void finalize_loss(
    const float* __restrict__ T4,
    const float* __restrict__ src_points, const float* __restrict__ tgt_points,
    const float* __restrict__ src_scores, const float* __restrict__ tgt_scores,
    const int* __restrict__ sidx, const int* __restrict__ tidx,
    const unsigned long long* __restrict__ row_best,
    const unsigned long long* __restrict__ col_best,
    float* __restrict__ out)
{
    const int tid = threadIdx.x;
    const float R00=T4[0],R01=T4[1],R02=T4[2],t0=T4[3];
    const float R10=T4[4],R11=T4[5],R12=T4[6],t1=T4[7];
    const float R20=T4[8],R21=T4[9],R22=T4[10],t2=T4[11];

    double S1 = 0.0, S0 = 0.0;
    float cnt = 0.f, sumres = 0.f, corr = 0.f;

    for (int i = tid; i < NTOT; i += 1024) {
        float label, score;
        if (i < N_POS) {
            int si = sidx[i];
            const float* p = src_points + (size_t)si * 3;
            float px = R00*p[0]+R01*p[1]+R02*p[2]+t0;
            float py = R10*p[0]+R11*p[1]+R12*p[2]+t1;
            float pz = R20*p[0]+R21*p[1]+R22*p[2]+t2;
            unsigned nn = unpackIdx(row_best[i]);
            const float* q = tgt_points + (size_t)tidx[nn] * 3;
            float dx = px-q[0], dy = py-q[1], dz = pz-q[2];
            label = (sqrtf(dx*dx+dy*dy+dz*dz) < 0.1f) ? 1.f : 0.f;
            score = src_scores[si];
        } else {
            int j = i - N_POS;
            int tj = tidx[j];
            const float* q = tgt_points + (size_t)tj * 3;
            unsigned nn = unpackIdx(col_best[j]);
            int si = sidx[nn];
            const float* p = src_points + (size_t)si * 3;
            float px = R00*p[0]+R01*p[1]+R02*p[2]+t0;
            float py = R10*p[0]+R11*p[1]+R12*p[2]+t1;
            float pz = R20*p[0]+R21*p[1]+R22*p[2]+t2;
            float dx = q[0]-px, dy = q[1]-py, dz = q[2]-pz;
            label = (sqrtf(dx*dx+dy*dy+dz*dz) < 0.1f) ? 1.f : 0.f;
            score = tgt_scores[tj];
        }
        cnt += label;
        float res = (score > 0.5f) ? 1.f : 0.f;
        sumres += res;
        corr += res * label;
        if (label > 0.5f) S1 += (double)(-logf(score));
        else              S0 += (double)(-logf(1.0f - score));
    }

    #pragma unroll
    for (int off = 32; off > 0; off >>= 1) {
        S1 += __shfl_down(S1, off);
        S0 += __shfl_down(S0, off);
        cnt += __shfl_down(cnt, off);
        sumres += __shfl_down(sumres, off);
        corr += __shfl_down(corr, off);
    }
    __shared__ double sh1[16], sh0[16];
    __shared__ float shc[16], shr[16], shco[16];
    int wid = tid >> 6, lane = tid & 63;
    if (lane == 0) { sh1[wid]=S1; sh0[wid]=S0; shc[wid]=cnt; shr[wid]=sumres; shco[wid]=corr; }
    __syncthreads();
    if (tid == 0) {
        double s1 = 0, s0 = 0; float c = 0, rr = 0, co = 0;
        for (int w = 0; w < 16; ++w) { s1+=sh1[w]; s0+=sh0[w]; c+=shc[w]; rr+=shr[w]; co+=shco[w]; }
        float nw = c / (float)NTOT;
        float loss = (float)((nw * s1 + (1.0 - (double)nw) * s0) / (double)NTOT);
        out[0] = loss;
        out[1] = co / (rr + 1e-12f);
        out[2] = co / (c + 1e-12f);
    }
}

extern "C" void kernel_launch(void* const* d_in, const int* in_sizes, int n_in,
                              void* d_out, int out_size, void* d_ws, size_t ws_size,
                              hipStream_t stream) {
    const float* T4         = (const float*)d_in[0];
    const float* src_points = (const float*)d_in[1];
    const float* tgt_points = (const float*)d_in[2];
    const float* src_scores = (const float*)d_in[3];
    const float* tgt_scores = (const float*)d_in[4];
    const float* src_feats  = (const float*)d_in[5];
    const float* tgt_feats  = (const float*)d_in[6];
    const int*   sidx       = (const int*)d_in[7];
    const int*   tidx       = (const int*)d_in[8];

    unsigned long long* row_best = (unsigned long long*)d_ws;
    unsigned long long* col_best = row_best + N_POS;
    float* out = (float*)d_out;

    hipLaunchKernelGGL(init_ws, dim3(64), dim3(256), 0, stream, row_best, 2 * N_POS);
    hipLaunchKernelGGL(gemm_argmax, dim3(N_POS / BM, N_POS / BN), dim3(256), 0, stream,
                       src_feats, tgt_feats, sidx, tidx, row_best, col_best);
    hipLaunchKernelGGL(finalize_loss, dim3(1), dim3(1024), 0, stream,
                       T4, src_points, tgt_points, src_scores, tgt_scores,
                       sidx, tidx, row_best, col_best, out);
}

// Round 3
// 191.574 us; speedup vs baseline: 5.5927x; 1.5508x over previous
//
#include <hip/hip_runtime.h>
#include <math.h>

#define N_POS 8192
#define FEAT 512
#define NTOT (2 * N_POS)
#define BM 128
#define BN 128

typedef __attribute__((ext_vector_type(8))) short bf16x8;
typedef __attribute__((ext_vector_type(4))) short s16x4;
typedef __attribute__((ext_vector_type(4))) float f32x4;

__device__ inline unsigned long long packMax(float v, unsigned idx) {
    unsigned u = __float_as_uint(v);
    u = (u & 0x80000000u) ? ~u : (u | 0x80000000u);
    return ((unsigned long long)u << 32) | (unsigned)(~idx);
}
__device__ inline unsigned unpackIdx(unsigned long long p) {
    return ~(unsigned)(p & 0xffffffffull);
}
__device__ inline short f2bf(float f) {
    unsigned u = __float_as_uint(f);
    return (short)((u + 0x7FFFu + ((u >> 16) & 1u)) >> 16);
}

__global__ void init_ws(unsigned long long* buf, int n) {
    int i = blockIdx.x * blockDim.x + threadIdx.x;
    if (i < n) buf[i] = 0ull;
}

// gather rows by idx and convert fp32 -> bf16 (RNE), linear output [8192][512]
__global__ __launch_bounds__(256) void gather_convert(
    const float* __restrict__ F, const int* __restrict__ idx, short* __restrict__ out)
{
    int t = blockIdx.x * 256 + threadIdx.x;   // one float4 per thread
    int i = t >> 7;                           // 128 float4 per row
    int k4 = t & 127;
    float4 v = *(const float4*)(F + (size_t)idx[i] * FEAT + k4 * 4);
    s16x4 o = { f2bf(v.x), f2bf(v.y), f2bf(v.z), f2bf(v.w) };
    *(s16x4*)(out + (size_t)i * FEAT + k4 * 4) = o;
}

// ---------------- fast path: bf16 MFMA GEMM + fused argmax ----------------
// LDS tile [128][64] bf16 per buffer; 16B chunk c of row r stored at c ^ (r&7)
__device__ inline bf16x8 frag(const short (*S)[64], int row, int chunk) {
    int c = chunk ^ (row & 7);
    return *(const bf16x8*)((const char*)S + row * 128 + c * 16);
}

__global__ __launch_bounds__(256) void gemm_bf16_argmax(
    const short* __restrict__ Abf, const short* __restrict__ Bbf,
    unsigned long long* __restrict__ row_best,
    unsigned long long* __restrict__ col_best)
{
    __shared__ __align__(16) short As[2][BM][64];
    __shared__ __align__(16) short Bs[2][BN][64];
    __shared__ unsigned long long redR[BM], redC[BN];

    const int tid = threadIdx.x;
    // XCD-aware bijective swizzle: 4096 blocks, 8 XCDs
    const int bid = blockIdx.x;
    const int swz = (bid & 7) * 512 + (bid >> 3);
    const int brow = (swz >> 6) * BM;
    const int bcol = (swz & 63) * BN;

    if (tid < BM) redR[tid] = 0ull; else redC[tid - BM] = 0ull;

    const int w = tid >> 6;
    const int lane = tid & 63;
    const int wm = w >> 1, wn = w & 1;
    const int l15 = lane & 15, kh = lane >> 4;

    // staging geometry: issue q = w*4+s covers rows q*8..q*8+7, lane -> (row=q*8+(l>>3), chunk=l&7)
    const int srow = lane >> 3;
    const int schk = lane & 7;
    const int scp  = schk ^ srow;   // pre-swizzled global chunk (inverse of read swizzle)

#define STAGE(buf, ks)                                                                   \
    {                                                                                    \
        _Pragma("unroll")                                                                \
        for (int s = 0; s < 4; ++s) {                                                    \
            int q = w * 4 + s;                                                           \
            int r = q * 8 + srow;                                                        \
            const short* ga = Abf + (size_t)(brow + r) * FEAT + (ks) * 64 + scp * 8;     \
            const short* gb = Bbf + (size_t)(bcol + r) * FEAT + (ks) * 64 + scp * 8;     \
            __builtin_amdgcn_global_load_lds(                                            \
                (const __attribute__((address_space(1))) unsigned int*)ga,               \
                (__attribute__((address_space(3))) unsigned int*)((char*)&As[buf][0][0] + q * 1024 + lane * 16), \
                16, 0, 0);                                                               \
            __builtin_amdgcn_global_load_lds(                                            \
                (const __attribute__((address_space(1))) unsigned int*)gb,               \
                (__attribute__((address_space(3))) unsigned int*)((char*)&Bs[buf][0][0] + q * 1024 + lane * 16), \
                16, 0, 0);                                                               \
        }                                                                                \
    }

    f32x4 acc[4][4];
    #pragma unroll
    for (int m = 0; m < 4; ++m)
        #pragma unroll
        for (int n = 0; n < 4; ++n)
            acc[m][n] = (f32x4)0.f;

    STAGE(0, 0);
    __syncthreads();

    int cur = 0;
    for (int ks = 0; ks < FEAT / 64; ++ks) {
        if (ks + 1 < FEAT / 64) STAGE(cur ^ 1, ks + 1);
        #pragma unroll
        for (int kb = 0; kb < 2; ++kb) {
            bf16x8 a[4], b[4];
            #pragma unroll
            for (int i = 0; i < 4; ++i) {
                a[i] = frag(As[cur], wm * 64 + i * 16 + l15, kb * 4 + kh);
                b[i] = frag(Bs[cur], wn * 64 + i * 16 + l15, kb * 4 + kh);
            }
            #pragma unroll
            for (int m = 0; m < 4; ++m)
                #pragma unroll
                for (int n = 0; n < 4; ++n)
                    acc[m][n] = __builtin_amdgcn_mfma_f32_16x16x32_bf16(a[m], b[n], acc[m][n], 0, 0, 0);
        }
        __syncthreads();
        cur ^= 1;
    }
#undef STAGE

    // ---- fused argmax epilogue (verified mapping) ----
    // lane holds C[row = wm*64 + m*16 + kh*4 + j][col = wn*64 + n*16 + l15]
    #pragma unroll
    for (int m = 0; m < 4; ++m) {
        #pragma unroll
        for (int j = 0; j < 4; ++j) {
            float best = acc[m][0][j]; int bn_ = 0;
            #pragma unroll
            for (int n = 1; n < 4; ++n)
                if (acc[m][n][j] > best) { best = acc[m][n][j]; bn_ = n; }
            unsigned long long p = packMax(best, (unsigned)(bcol + wn * 64 + bn_ * 16 + l15));
            #pragma unroll
            for (int mask = 1; mask <= 8; mask <<= 1) {
                unsigned long long q = __shfl_xor(p, mask);
                if (q > p) p = q;
            }
            if (l15 == 0)
                atomicMax(&redR[wm * 64 + m * 16 + kh * 4 + j], p);
        }
    }
    #pragma unroll
    for (int n = 0; n < 4; ++n) {
        float best = acc[0][n][0]; int bm_ = 0, bj_ = 0;
        #pragma unroll
        for (int m = 0; m < 4; ++m)
            #pragma unroll
            for (int j = 0; j < 4; ++j)
                if (acc[m][n][j] > best) { best = acc[m][n][j]; bm_ = m; bj_ = j; }
        unsigned long long p = packMax(best, (unsigned)(brow + wm * 64 + bm_ * 16 + kh * 4 + bj_));
        #pragma unroll
        for (int mask = 16; mask <= 32; mask <<= 1) {
            unsigned long long q = __shfl_xor(p, mask);
            if (q > p) p = q;
        }
        if (kh == 0)
            atomicMax(&redC[wn * 64 + n * 16 + l15], p);
    }
    __syncthreads();
    if (tid < BM) atomicMax(&row_best[brow + tid], redR[tid]);
    else          atomicMax(&col_best[bcol + tid - BM], redC[tid - BM]);
}

// ---------------- fallback path (round-2 kernel, needs only 128 KB ws) ----------------
__device__ inline void split8(const float* f, bf16x8& hi, bf16x8& lo) {
    #pragma unroll
    for (int i = 0; i < 8; ++i) {
        unsigned u = __float_as_uint(f[i]);
        unsigned hr = (u + 0x7FFFu + ((u >> 16) & 1u)) >> 16;
        hi[i] = (short)hr;
        float lf = f[i] - __uint_as_float(hr << 16);
        lo[i] = (short)(__float_as_uint(lf) >> 16);
    }
}
__device__ inline bf16x8 read_frag_fb(const short (*S)[64], int row, int chunk) {
    int c = chunk ^ (row & 7);
    return *(const bf16x8*)&S[row][c * 8];
}
__device__ inline void write_chunk_fb(short (*S)[64], int row, int chunk, bf16x8 v) {
    int c = chunk ^ (row & 7);
    *(bf16x8*)&S[row][c * 8] = v;
}

__global__ __launch_bounds__(256) void gemm_argmax_fb(
    const float* __restrict__ A, const float* __restrict__ B,
    const int* __restrict__ sidx, const int* __restrict__ tidx,
    unsigned long long* __restrict__ row_best,
    unsigned long long* __restrict__ col_best)
{
    __shared__ short As[BM][64];
    __shared__ short Bs[BN][64];
    __shared__ int sI[BM], tI[BN];
    __shared__ unsigned long long redR[BM], redC[BN];

    const int tid = threadIdx.x;
    const int brow = blockIdx.x * BM;
    const int bcol = blockIdx.y * BN;

    if (tid < BM) { sI[tid] = sidx[brow + tid]; redR[tid] = 0ull; }
    else          { tI[tid - BM] = tidx[bcol + tid - BM]; redC[tid - BM] = 0ull; }
    __syncthreads();

    const int r = tid >> 1;
    const int h = tid & 1;
    const float* aBase = A + (size_t)sI[r] * FEAT + h * 16;
    const float* bBase = B + (size_t)tI[r] * FEAT + h * 16;

    const int w = tid >> 6;
    const int wm = w >> 1, wn = w & 1;
    const int lane = tid & 63;
    const int l15 = lane & 15, khalf = lane >> 4;

    f32x4 acc[4][4];
    #pragma unroll
    for (int m = 0; m < 4; ++m)
        #pragma unroll
        for (int n = 0; n < 4; ++n)
            acc[m][n] = (f32x4)0.f;

    float4 pa[4], pb[4];
    #pragma unroll
    for (int i = 0; i < 4; ++i) {
        pa[i] = *(const float4*)(aBase + i * 4);
        pb[i] = *(const float4*)(bBase + i * 4);
    }

    for (int ks = 0; ks < FEAT / 32; ++ks) {
        bf16x8 ha0, ha1, la0, la1, hb0, hb1, lb0, lb1;
        split8((const float*)&pa[0], ha0, la0);
        split8((const float*)&pa[2], ha1, la1);
        split8((const float*)&pb[0], hb0, lb0);
        split8((const float*)&pb[2], hb1, lb1);
        write_chunk_fb(As, r, 2 * h,     ha0);
        write_chunk_fb(As, r, 2 * h + 1, ha1);
        write_chunk_fb(As, r, 4 + 2 * h, la0);
        write_chunk_fb(As, r, 5 + 2 * h, la1);
        write_chunk_fb(Bs, r, 2 * h,     hb0);
        write_chunk_fb(Bs, r, 2 * h + 1, hb1);
        write_chunk_fb(Bs, r, 4 + 2 * h, lb0);
        write_chunk_fb(Bs, r, 5 + 2 * h, lb1);
        __syncthreads();

        if (ks + 1 < FEAT / 32) {
            const float* ap = aBase + (ks + 1) * 32;
            const float* bp = bBase + (ks + 1) * 32;
            #pragma unroll
            for (int i = 0; i < 4; ++i) {
                pa[i] = *(const float4*)(ap + i * 4);
                pb[i] = *(const float4*)(bp + i * 4);
            }
        }

        bf16x8 ah[4], al[4], bh[4], bl[4];
        #pragma unroll
        for (int i = 0; i < 4; ++i) {
            int ra = wm * 64 + i * 16 + l15;
            ah[i] = read_frag_fb(As, ra, khalf);
            al[i] = read_frag_fb(As, ra, 4 + khalf);
            int rb = wn * 64 + i * 16 + l15;
            bh[i] = read_frag_fb(Bs, rb, khalf);
            bl[i] = read_frag_fb(Bs, rb, 4 + khalf);
        }
        #pragma unroll
        for (int m = 0; m < 4; ++m)
            #pragma unroll
            for (int n = 0; n < 4; ++n) {
                acc[m][n] = __builtin_amdgcn_mfma_f32_16x16x32_bf16(ah[m], bh[n], acc[m][n], 0, 0, 0);
                acc[m][n] = __builtin_amdgcn_mfma_f32_16x16x32_bf16(ah[m], bl[n], acc[m][n], 0, 0, 0);
                acc[m][n] = __builtin_amdgcn_mfma_f32_16x16x32_bf16(al[m], bh[n], acc[m][n], 0, 0, 0);
            }
        __syncthreads();
    }

    #pragma unroll
    for (int m = 0; m < 4; ++m) {
        #pragma unroll
        for (int j = 0; j < 4; ++j) {
            float best = acc[m][0][j]; int bn_ = 0;
            #pragma unroll
            for (int n = 1; n < 4; ++n)
                if (acc[m][n][j] > best) { best = acc[m][n][j]; bn_ = n; }
            unsigned long long p = packMax(best, (unsigned)(bcol + wn * 64 + bn_ * 16 + l15));
            #pragma unroll
            for (int mask = 1; mask <= 8; mask <<= 1) {
                unsigned long long q = __shfl_xor(p, mask);
                if (q > p) p = q;
            }
            if (l15 == 0)
                atomicMax(&redR[wm * 64 + m * 16 + khalf * 4 + j], p);
        }
    }
    #pragma unroll
    for (int n = 0; n < 4; ++n) {
        float best = acc[0][n][0]; int bm_ = 0, bj_ = 0;
        #pragma unroll
        for (int m = 0; m < 4; ++m)
            #pragma unroll
            for (int j = 0; j < 4; ++j)
                if (acc[m][n][j] > best) { best = acc[m][n][j]; bm_ = m; bj_ = j; }
        unsigned long long p = packMax(best, (unsigned)(brow + wm * 64 + bm_ * 16 + khalf * 4 + bj_));
        #pragma unroll
        for (int mask = 16; mask <= 32; mask <<= 1) {
            unsigned long long q = __shfl_xor(p, mask);
            if (q > p) p = q;
        }
        if (khalf == 0)
            atomicMax(&redC[wn * 64 + n * 16 + l15], p);
    }
    __syncthreads();
    if (tid < BM) atomicMax(&row_best[brow + tid], redR[tid]);
    else          atomicMax(&col_best[bcol + tid - BM], redC[tid - BM]);
}

__global__ __launch_bounds__(1024) void finalize_loss(
    const float* __restrict__ T4,
    const float* __restrict__ src_points, const float* __restrict__ tgt_points,
    const float* __restrict__ src_scores, const float* __restrict__ tgt_scores,
    const int* __restrict__ sidx, const int* __restrict__ tidx,
    const unsigned long long* __restrict__ row_best,
    const unsigned long long* __restrict__ col_best,
    float* __restrict__ out)
{
    const int tid = threadIdx.x;
    const float R00=T4[0],R01=T4[1],R02=T4[2],t0=T4[3];
    const float R10=T4[4],R11=T4[5],R12=T4[6],t1=T4[7];
    const float R20=T4[8],R21=T4[9],R22=T4[10],t2=T4[11];

    double S1 = 0.0, S0 = 0.0;
    float cnt = 0.f, sumres = 0.f, corr = 0.f;

    for (int i = tid; i < NTOT; i += 1024) {
        float label, score;
        if (i < N_POS) {
            int si = sidx[i];
            const float* p = src_points + (size_t)si * 3;
            float px = R00*p[0]+R01*p[1]+R02*p[2]+t0;
            float py = R10*p[0]+R11*p[1]+R12*p[2]+t1;
            float pz = R20*p[0]+R21*p[1]+R22*p[2]+t2;
            unsigned nn = unpackIdx(row_best[i]);
            const float* q = tgt_points + (size_t)tidx[nn] * 3;
            float dx = px-q[0], dy = py-q[1], dz = pz-q[2];
            label = (sqrtf(dx*dx+dy*dy+dz*dz) < 0.1f) ? 1.f : 0.f;
            score = src_scores[si];
        } else {
            int j = i - N_POS;
            int tj = tidx[j];
            const float* q = tgt_points + (size_t)tj * 3;
            unsigned nn = unpackIdx(col_best[j]);
            int si = sidx[nn];
            const float* p = src_points + (size_t)si * 3;
            float px = R00*p[0]+R01*p[1]+R02*p[2]+t0;
            float py = R10*p[0]+R11*p[1]+R12*p[2]+t1;
            float pz = R20*p[0]+R21*p[1]+R22*p[2]+t2;
            float dx = q[0]-px, dy = q[1]-py, dz = q[2]-pz;
            label = (sqrtf(dx*dx+dy*dy+dz*dz) < 0.1f) ? 1.f : 0.f;
            score = tgt_scores[tj];
        }
        cnt += label;
        float res = (score > 0.5f) ? 1.f : 0.f;
        sumres += res;
        corr += res * label;
        if (label > 0.5f) S1 += (double)(-logf(score));
        else              S0 += (double)(-logf(1.0f - score));
    }

    #pragma unroll
    for (int off = 32; off > 0; off >>= 1) {
        S1 += __shfl_down(S1, off);
        S0 += __shfl_down(S0, off);
        cnt += __shfl_down(cnt, off);
        sumres += __shfl_down(sumres, off);
        corr += __shfl_down(corr, off);
    }
    __shared__ double sh1[16], sh0[16];
    __shared__ float shc[16], shr[16], shco[16];
    int wid = tid >> 6, lane = tid & 63;
    if (lane == 0) { sh1[wid]=S1; sh0[wid]=S0; shc[wid]=cnt; shr[wid]=sumres; shco[wid]=corr; }
    __syncthreads();
    if (tid == 0) {
        double s1 = 0, s0 = 0; float c = 0, rr = 0, co = 0;
        for (int w = 0; w < 16; ++w) { s1+=sh1[w]; s0+=sh0[w]; c+=shc[w]; rr+=shr[w]; co+=shco[w]; }
        float nw = c / (float)NTOT;
        float loss = (float)((nw * s1 + (1.0 - (double)nw) * s0) / (double)NTOT);
        out[0] = loss;
        out[1] = co / (rr + 1e-12f);
        out[2] = co / (c + 1e-12f);
    }
}

extern "C" void kernel_launch(void* const* d_in, const int* in_sizes, int n_in,
                              void* d_out, int out_size, void* d_ws, size_t ws_size,
                              hipStream_t stream) {
    const float* T4         = (const float*)d_in[0];
    const float* src_points = (const float*)d_in[1];
    const float* tgt_points = (const float*)d_in[2];
    const float* src_scores = (const float*)d_in[3];
    const float* tgt_scores = (const float*)d_in[4];
    const float* src_feats  = (const float*)d_in[5];
    const float* tgt_feats  = (const float*)d_in[6];
    const int*   sidx       = (const int*)d_in[7];
    const int*   tidx       = (const int*)d_in[8];

    unsigned long long* row_best = (unsigned long long*)d_ws;
    unsigned long long* col_best = row_best + N_POS;
    short* Abf = (short*)((char*)d_ws + 2 * N_POS * sizeof(unsigned long long));
    short* Bbf = Abf + (size_t)N_POS * FEAT;
    float* out = (float*)d_out;

    const size_t needed = 2ull * N_POS * sizeof(unsigned long long)
                        + 2ull * N_POS * FEAT * sizeof(short);
    const bool fast = ws_size >= needed;

    hipLaunchKernelGGL(init_ws, dim3(64), dim3(256), 0, stream, row_best, 2 * N_POS);
    if (fast) {
        hipLaunchKernelGGL(gather_convert, dim3(N_POS * FEAT / 4 / 256), dim3(256), 0, stream,
                           src_feats, sidx, Abf);
        hipLaunchKernelGGL(gather_convert, dim3(N_POS * FEAT / 4 / 256), dim3(256), 0, stream,
                           tgt_feats, tidx, Bbf);
        hipLaunchKernelGGL(gemm_bf16_argmax, dim3((N_POS / BM) * (N_POS / BN)), dim3(256), 0, stream,
                           Abf, Bbf, row_best, col_best);
    } else {
        hipLaunchKernelGGL(gemm_argmax_fb, dim3(N_POS / BM, N_POS / BN), dim3(256), 0, stream,
                           src_feats, tgt_feats, sidx, tidx, row_best, col_best);
    }
    hipLaunchKernelGGL(finalize_loss, dim3(1), dim3(1024), 0, stream,
                       T4, src_points, tgt_points, src_scores, tgt_scores,
                       sidx, tidx, row_best, col_best, out);
}

// Round 4
// 142.681 us; speedup vs baseline: 7.5091x; 1.3427x over previous
//
#include <hip/hip_runtime.h>
#include <math.h>

#define N_POS 8192
#define FEAT 512
#define NTOT (2 * N_POS)
#define BM 128
#define BN 128

typedef __attribute__((ext_vector_type(8))) short bf16x8;
typedef __attribute__((ext_vector_type(4))) short s16x4;
typedef __attribute__((ext_vector_type(4))) float f32x4;

__device__ inline unsigned long long packMax(float v, unsigned idx) {
    unsigned u = __float_as_uint(v);
    u = (u & 0x80000000u) ? ~u : (u | 0x80000000u);
    return ((unsigned long long)u << 32) | (unsigned)(~idx);
}
__device__ inline unsigned unpackIdx(unsigned long long p) {
    return ~(unsigned)(p & 0xffffffffull);
}
__device__ inline short f2bf(float f) {
    unsigned u = __float_as_uint(f);
    return (short)((u + 0x7FFFu + ((u >> 16) & 1u)) >> 16);
}

__global__ void init_ws(unsigned long long* buf, int n) {
    int i = blockIdx.x * blockDim.x + threadIdx.x;
    if (i < n) buf[i] = 0ull;
}

// gather rows by idx and convert fp32 -> bf16 (RNE); both matrices in one launch
__global__ __launch_bounds__(256) void gather_convert2(
    const float* __restrict__ F0, const int* __restrict__ idx0, short* __restrict__ out0,
    const float* __restrict__ F1, const int* __restrict__ idx1, short* __restrict__ out1)
{
    const int per = N_POS * FEAT / 4;         // float4 slots per matrix
    int t = blockIdx.x * 256 + threadIdx.x;
    const float* F; const int* idx; short* out;
    if (t < per) { F = F0; idx = idx0; out = out0; }
    else         { F = F1; idx = idx1; out = out1; t -= per; }
    int i  = t >> 7;                          // 128 float4 per row
    int k4 = t & 127;
    float4 v = *(const float4*)(F + (size_t)idx[i] * FEAT + k4 * 4);
    s16x4 o = { f2bf(v.x), f2bf(v.y), f2bf(v.z), f2bf(v.w) };
    *(s16x4*)(out + (size_t)i * FEAT + k4 * 4) = o;
}

// LDS tile [128][64] bf16, single-buffered; 16B chunk c of row r stored at slot c^(r&7)
__device__ inline bf16x8 frag(const short (*S)[64], int row, int chunk) {
    int c = chunk ^ (row & 7);
    return *(const bf16x8*)((const char*)S + row * 128 + c * 16);
}

__global__ __launch_bounds__(256, 4) void gemm_bf16_argmax(
    const short* __restrict__ Abf, const short* __restrict__ Bbf,
    unsigned long long* __restrict__ row_best,
    unsigned long long* __restrict__ col_best)
{
    __shared__ __align__(16) short As[BM][64];   // 16 KB
    __shared__ __align__(16) short Bs[BN][64];   // 16 KB
    __shared__ unsigned long long redR[BM], redC[BN];  // 4 KB  -> 36.9 KB total, 4 blocks/CU

    const int tid = threadIdx.x;
    // 2-level XCD swizzle: xcd slab = 8 block-rows x 64 cols, walked in 4-col groups
    // (L2 working set per group: 8x128KB A + 4x128KB B = 1.5 MB < 4 MB)
    const int bid  = blockIdx.x;
    const int xcd  = bid & 7;
    const int loc  = bid >> 3;        // 0..511
    const int cg   = loc >> 5;        // 0..15 : column group of 4
    const int r8   = (loc & 31) >> 2; // 0..7  : row within slab
    const int c4   = loc & 3;         // 0..3  : col within group
    const int brow = (xcd * 8 + r8) * BM;
    const int bcol = (cg * 4 + c4) * BN;

    if (tid < BM) redR[tid] = 0ull; else redC[tid - BM] = 0ull;

    const int w = tid >> 6;
    const int lane = tid & 63;
    const int wm = w >> 1, wn = w & 1;
    const int l15 = lane & 15, kh = lane >> 4;

    // staging: issue q = w*4+s covers rows q*8..q*8+7; lane -> (row=q*8+(l>>3), slot=l&7)
    const int srow = lane >> 3;
    const int schk = lane & 7;
    const int scp  = schk ^ srow;     // pre-swizzled global chunk (inverse of read swizzle)

    f32x4 acc[4][4];
    #pragma unroll
    for (int m = 0; m < 4; ++m)
        #pragma unroll
        for (int n = 0; n < 4; ++n)
            acc[m][n] = (f32x4)0.f;

    for (int ks = 0; ks < FEAT / 64; ++ks) {
        #pragma unroll
        for (int s = 0; s < 4; ++s) {
            int q = w * 4 + s;
            int r = q * 8 + srow;
            const short* ga = Abf + (size_t)(brow + r) * FEAT + ks * 64 + scp * 8;
            const short* gb = Bbf + (size_t)(bcol + r) * FEAT + ks * 64 + scp * 8;
            __builtin_amdgcn_global_load_lds(
                (const __attribute__((address_space(1))) unsigned int*)ga,
                (__attribute__((address_space(3))) unsigned int*)((char*)&As[0][0] + q * 1024 + lane * 16),
                16, 0, 0);
            __builtin_amdgcn_global_load_lds(
                (const __attribute__((address_space(1))) unsigned int*)gb,
                (__attribute__((address_space(3))) unsigned int*)((char*)&Bs[0][0] + q * 1024 + lane * 16),
                16, 0, 0);
        }
        __syncthreads();   // drains vmcnt(0): staged tile visible

        #pragma unroll
        for (int kb = 0; kb < 2; ++kb) {
            bf16x8 a[4], b[4];
            #pragma unroll
            for (int i = 0; i < 4; ++i) {
                a[i] = frag(As, wm * 64 + i * 16 + l15, kb * 4 + kh);
                b[i] = frag(Bs, wn * 64 + i * 16 + l15, kb * 4 + kh);
            }
            #pragma unroll
            for (int m = 0; m < 4; ++m)
                #pragma unroll
                for (int n = 0; n < 4; ++n)
                    acc[m][n] = __builtin_amdgcn_mfma_f32_16x16x32_bf16(a[m], b[n], acc[m][n], 0, 0, 0);
        }
        __syncthreads();   // all reads done before next STAGE overwrites
    }

    // ---- fused argmax epilogue (verified mapping) ----
    // lane holds C[row = wm*64 + m*16 + kh*4 + j][col = wn*64 + n*16 + l15]
    #pragma unroll
    for (int m = 0; m < 4; ++m) {
        #pragma unroll
        for (int j = 0; j < 4; ++j) {
            float best = acc[m][0][j]; int bn_ = 0;
            #pragma unroll
            for (int n = 1; n < 4; ++n)
                if (acc[m][n][j] > best) { best = acc[m][n][j]; bn_ = n; }
            unsigned long long p = packMax(best, (unsigned)(bcol + wn * 64 + bn_ * 16 + l15));
            #pragma unroll
            for (int mask = 1; mask <= 8; mask <<= 1) {
                unsigned long long q = __shfl_xor(p, mask);
                if (q > p) p = q;
            }
            if (l15 == 0)
                atomicMax(&redR[wm * 64 + m * 16 + kh * 4 + j], p);
        }
    }
    #pragma unroll
    for (int n = 0; n < 4; ++n) {
        float best = acc[0][n][0]; int bm_ = 0, bj_ = 0;
        #pragma unroll
        for (int m = 0; m < 4; ++m)
            #pragma unroll
            for (int j = 0; j < 4; ++j)
                if (acc[m][n][j] > best) { best = acc[m][n][j]; bm_ = m; bj_ = j; }
        unsigned long long p = packMax(best, (unsigned)(brow + wm * 64 + bm_ * 16 + kh * 4 + bj_));
        #pragma unroll
        for (int mask = 16; mask <= 32; mask <<= 1) {
            unsigned long long q = __shfl_xor(p, mask);
            if (q > p) p = q;
        }
        if (kh == 0)
            atomicMax(&redC[wn * 64 + n * 16 + l15], p);
    }
    __syncthreads();
    if (tid < BM) atomicMax(&row_best[brow + tid], redR[tid]);
    else          atomicMax(&col_best[bcol + tid - BM], redC[tid - BM]);
}

__global__ __launch_bounds__(1024) void finalize_loss(
    const float* __restrict__ T4,
    const float* __restrict__ src_points, const float* __restrict__ tgt_points,
    const float* __restrict__ src_scores, const float* __restrict__ tgt_scores,
    const int* __restrict__ sidx, const int* __restrict__ tidx,
    const unsigned long long* __restrict__ row_best,
    const unsigned long long* __restrict__ col_best,
    float* __restrict__ out)
{
    const int tid = threadIdx.x;
    const float R00=T4[0],R01=T4[1],R02=T4[2],t0=T4[3];
    const float R10=T4[4],R11=T4[5],R12=T4[6],t1=T4[7];
    const float R20=T4[8],R21=T4[9],R22=T4[10],t2=T4[11];

    double S1 = 0.0, S0 = 0.0;
    float cnt = 0.f, sumres = 0.f, corr = 0.f;

    for (int i = tid; i < NTOT; i += 1024) {
        float label, score;
        if (i < N_POS) {
            int si = sidx[i];
            const float* p = src_points + (size_t)si * 3;
            float px = R00*p[0]+R01*p[1]+R02*p[2]+t0;
            float py = R10*p[0]+R11*p[1]+R12*p[2]+t1;
            float pz = R20*p[0]+R21*p[1]+R22*p[2]+t2;
            unsigned nn = unpackIdx(row_best[i]);
            const float* q = tgt_points + (size_t)tidx[nn] * 3;
            float dx = px-q[0], dy = py-q[1], dz = pz-q[2];
            label = (sqrtf(dx*dx+dy*dy+dz*dz) < 0.1f) ? 1.f : 0.f;
            score = src_scores[si];
        } else {
            int j = i - N_POS;
            int tj = tidx[j];
            const float* q = tgt_points + (size_t)tj * 3;
            unsigned nn = unpackIdx(col_best[j]);
            int si = sidx[nn];
            const float* p = src_points + (size_t)si * 3;
            float px = R00*p[0]+R01*p[1]+R02*p[2]+t0;
            float py = R10*p[0]+R11*p[1]+R12*p[2]+t1;
            float pz = R20*p[0]+R21*p[1]+R22*p[2]+t2;
            float dx = q[0]-px, dy = q[1]-py, dz = q[2]-pz;
            label = (sqrtf(dx*dx+dy*dy+dz*dz) < 0.1f) ? 1.f : 0.f;
            score = tgt_scores[tj];
        }
        cnt += label;
        float res = (score > 0.5f) ? 1.f : 0.f;
        sumres += res;
        corr += res * label;
        if (label > 0.5f) S1 += (double)(-logf(score));
        else              S0 += (double)(-logf(1.0f - score));
    }

    #pragma unroll
    for (int off = 32; off > 0; off >>= 1) {
        S1 += __shfl_down(S1, off);
        S0 += __shfl_down(S0, off);
        cnt += __shfl_down(cnt, off);
        sumres += __shfl_down(sumres, off);
        corr += __shfl_down(corr, off);
    }
    __shared__ double sh1[16], sh0[16];
    __shared__ float shc[16], shr[16], shco[16];
    int wid = tid >> 6, lane = tid & 63;
    if (lane == 0) { sh1[wid]=S1; sh0[wid]=S0; shc[wid]=cnt; shr[wid]=sumres; shco[wid]=corr; }
    __syncthreads();
    if (tid == 0) {
        double s1 = 0, s0 = 0; float c = 0, rr = 0, co = 0;
        for (int w = 0; w < 16; ++w) { s1+=sh1[w]; s0+=sh0[w]; c+=shc[w]; rr+=shr[w]; co+=shco[w]; }
        float nw = c / (float)NTOT;
        float loss = (float)((nw * s1 + (1.0 - (double)nw) * s0) / (double)NTOT);
        out[0] = loss;
        out[1] = co / (rr + 1e-12f);
        out[2] = co / (c + 1e-12f);
    }
}

extern "C" void kernel_launch(void* const* d_in, const int* in_sizes, int n_in,
                              void* d_out, int out_size, void* d_ws, size_t ws_size,
                              hipStream_t stream) {
    const float* T4         = (const float*)d_in[0];
    const float* src_points = (const float*)d_in[1];
    const float* tgt_points = (const float*)d_in[2];
    const float* src_scores = (const float*)d_in[3];
    const float* tgt_scores = (const float*)d_in[4];
    const float* src_feats  = (const float*)d_in[5];
    const float* tgt_feats  = (const float*)d_in[6];
    const int*   sidx       = (const int*)d_in[7];
    const int*   tidx       = (const int*)d_in[8];

    unsigned long long* row_best = (unsigned long long*)d_ws;
    unsigned long long* col_best = row_best + N_POS;
    short* Abf = (short*)((char*)d_ws + 2 * N_POS * sizeof(unsigned long long));
    short* Bbf = Abf + (size_t)N_POS * FEAT;
    float* out = (float*)d_out;

    hipLaunchKernelGGL(init_ws, dim3(64), dim3(256), 0, stream, row_best, 2 * N_POS);
    hipLaunchKernelGGL(gather_convert2, dim3(2 * N_POS * FEAT / 4 / 256), dim3(256), 0, stream,
                       src_feats, sidx, Abf, tgt_feats, tidx, Bbf);
    hipLaunchKernelGGL(gemm_bf16_argmax, dim3((N_POS / BM) * (N_POS / BN)), dim3(256), 0, stream,
                       Abf, Bbf, row_best, col_best);
    hipLaunchKernelGGL(finalize_loss, dim3(1), dim3(1024), 0, stream,
                       T4, src_points, tgt_points, src_scores, tgt_scores,
                       sidx, tidx, row_best, col_best, out);
}